// Round 1
// baseline (99.663 us; speedup 1.0000x reference)
//
#include <hip/hip_runtime.h>

// DIN encoder. B=8, N=512, D=64, H=64. Two launches:
//   prep   — weight transforms, hq, hk-scatter, X B-frags, enc-X B-frags
//   k2_main— 1024 blocks × 4 waves; block = (band via LUT, b, slice).
// R12: (a) k2 is LDS-read-bound (48KB ds_read + 12KB DMA-write per
//      block-round ≈ 770 LDS cyc; ×34 rounds/CU ≈ 11 µs). Move the 4
//      enc-X frags (e0..e3) to direct global b128 loads: all 4 waves hit
//      the same L1/L2-resident 4KB chunk, LDS pipe load drops by 1/3 and
//      bufE + its DMA disappear (LDS 24.3->16.3 KB/block).
//      (b) prep: 256 blocks × 16 rows (was 1024 × 4) — the 64KB W1
//      transform load per block was 67 MB of L2 traffic for 4 rows each.
// R11: band LUT balances per-CU round totals; global_load_lds async DMA
//      staging for the score frags (m97 pattern).
// R3 lesson: tight VGPR caps -> scratch spill. Keep (256,2).
#define NB 8
#define NN 512

// ws layout (float offsets)
#define WS_WMF 0        // Wm A-frag-major fp32 [8 slot][64 lane][8]          4096
#define WS_HQ  4096     // hq fp32 [B*N][64]                                262144
#define WS_BF  266240   // B-frags bf16 [B][32 t][4 c][64 lane][8]   (262144 fl)
#define WS_XE  528384   // enc-X bf16 [B][16 c32][4 nt][64 lane][8]  (131072 fl)

typedef float fx4 __attribute__((ext_vector_type(4)));
typedef short sx8 __attribute__((ext_vector_type(8)));
typedef int   ix4 __attribute__((ext_vector_type(4)));

static __device__ inline unsigned short f2bf(float f) {
    unsigned u = __float_as_uint(f);
    return (unsigned short)((u + 0x7FFFu + ((u >> 16) & 1u)) >> 16);  // RNE
}

// async 16B/lane global -> LDS DMA (gfx950). Lanes must be contiguous:
// caller passes per-thread g/l with lane-consecutive 16B addresses.
static __device__ inline void async_cp16(const void* g, void* l) {
    __builtin_amdgcn_global_load_lds(
        (const __attribute__((address_space(1))) unsigned int*)g,
        (__attribute__((address_space(3))) unsigned int*)l, 16, 0, 0);
}

// ---------------- fused prep: 256 blocks × 16 rows ----------------
__global__ __launch_bounds__(256) void prep(const float* __restrict__ x,
                                            const float* __restrict__ vm,
                                            const float* __restrict__ W1,
                                            const float* __restrict__ b1,
                                            float* __restrict__ ws) {
    __shared__ float lwq[64 * 68];   // (Wq+Wd)  [h][d], stride 68 (16B-aligned)
    __shared__ float lwk[64 * 68];   // (Wk-Wd)  [h][d]
    __shared__ float xs[1024];       // 16 rows of x
    const int t = threadIdx.x;
    const int blk = blockIdx.x;      // 0..255

    {
        int d = t & 63, hb = t >> 6;
        #pragma unroll 4
        for (int i = 0; i < 16; ++i) {
            int h = i * 4 + hb;
            float a = W1[h * 256 + d];
            float bb = W1[h * 256 + 64 + d];
            float c = W1[h * 256 + 128 + d];
            lwq[h * 68 + d] = a + c;
            lwk[h * 68 + d] = bb - c;
        }
    }
    const int r0 = blk * 16;
    #pragma unroll
    for (int i = 0; i < 4; ++i)
        xs[i * 256 + t] = x[r0 * 64 + i * 256 + t];
    __syncthreads();

    // hq + hk for this block's 16 rows (4 row-groups; row = wave, h = lane)
    {
        int r4 = t >> 6, h = t & 63;
        const fx4* wqv = (const fx4*)(lwq + h * 68);
        const fx4* wkv = (const fx4*)(lwk + h * 68);
        float bh = b1[h];
        unsigned short* bfp = (unsigned short*)(ws + WS_BF);
        #pragma unroll 1
        for (int g = 0; g < 4; ++g) {
            int r = g * 4 + r4;
            const fx4* xr = (const fx4*)(xs + r * 64);
            float aq = bh, ak = 0.f;
            #pragma unroll
            for (int dd = 0; dd < 16; ++dd) {
                fx4 xv = xr[dd];
                fx4 wq = wqv[dd];
                fx4 wk = wkv[dd];
                aq = fmaf(xv[0], wq[0], aq); aq = fmaf(xv[1], wq[1], aq);
                aq = fmaf(xv[2], wq[2], aq); aq = fmaf(xv[3], wq[3], aq);
                ak = fmaf(xv[0], wk[0], ak); ak = fmaf(xv[1], wk[1], ak);
                ak = fmaf(xv[2], wk[2], ak); ak = fmaf(xv[3], wk[3], ak);
            }
            int row = r0 + r;
            (ws + WS_HQ)[row * 64 + h] = aq;
            // scatter hk into B-frag chunk c=2+(h>>5)
            int bb = row >> 9, k = row & 511;
            int tt = k >> 4, nn = k & 15;
            int c = 2 + (h >> 5);
            int qd = (h >> 3) & 3, j = h & 7;
            int ln = qd * 16 + nn;
            bfp[((((bb * 32 + tt) * 4 + c) * 64 + ln) << 3) + j] = f2bf(ak);
        }
    }

    // staging: every block owns one (b, t5) pair
    {
        int b = blk >> 5, t5 = blk & 31;
        // X -> BF chunks 0/1
        if (t < 128) {
            unsigned short* bfp = (unsigned short*)(ws + WS_BF);
            int c = t >> 6, L = t & 63;
            int nn = L & 15, qd = L >> 4;
            const float* src = x + ((b * 512 + t5 * 16 + nn) * 64 + c * 32 + qd * 8);
            fx4 v0 = *(const fx4*)src;
            fx4 v1 = *(const fx4*)(src + 4);
            uint4 o;
            o.x = (unsigned)f2bf(v0[0]) | ((unsigned)f2bf(v0[1]) << 16);
            o.y = (unsigned)f2bf(v0[2]) | ((unsigned)f2bf(v0[3]) << 16);
            o.z = (unsigned)f2bf(v1[0]) | ((unsigned)f2bf(v1[1]) << 16);
            o.w = (unsigned)f2bf(v1[2]) | ((unsigned)f2bf(v1[3]) << 16);
            *(uint4*)(bfp + ((((b * 32 + t5) * 4 + c) * 64 + L) << 3)) = o;
        }
        // masked X -> enc B-frags (XE)
        {
            unsigned short* xep = (unsigned short*)(ws + WS_XE);
            int c32 = t5 >> 1, half = t5 & 1;
            int nt = t >> 6, r = t & 63;
            int L = half * 32 + (r & 31);
            int j0 = (r >> 5) * 4;
            int quad = L >> 4, nn = L & 15;
            unsigned short u[4];
            #pragma unroll
            for (int i = 0; i < 4; ++i) {
                int key = c32 * 32 + quad * 8 + j0 + i;
                float v = x[(b * 512 + key) * 64 + nt * 16 + nn] * vm[b * 512 + key];
                u[i] = f2bf(v);
            }
            uint2 o;
            o.x = (unsigned)u[0] | ((unsigned)u[1] << 16);
            o.y = (unsigned)u[2] | ((unsigned)u[3] << 16);
            *(uint2*)(xep + (((((b * 16 + c32) * 4 + nt) * 64 + L) << 3) + j0)) = o;
        }
    }
    if (blk < 2) {
        // Wm A-fragment-major
        float* wmf = ws + WS_WMF;
        int e = blk * 256 + t;               // 0..511
        int slot = e >> 6, lane = e & 63;
        int ht = slot >> 1, hf = slot & 1;
        int mm = lane & 15, qd = lane >> 4;
        int h = ht * 16 + mm;
        int dbase = hf * 32 + qd * 8;
        #pragma unroll
        for (int j = 0; j < 8; ++j)
            wmf[e * 8 + j] = W1[h * 256 + 192 + dbase + j];
    }
}

// ------- main: 1024 blocks, band LUT balanced, async DMA staging -------
__global__ __launch_bounds__(256, 2) void k2_main(const float* __restrict__ x,
                                                  const float* __restrict__ prelu_a,
                                                  const float* __restrict__ W2,
                                                  const float* __restrict__ b2,
                                                  const float* __restrict__ ws,
                                                  float* __restrict__ out) {
    const int tid  = threadIdx.x;
    const int lane = tid & 63;
    const int w    = tid >> 6;            // 0..3
    const int blk  = blockIdx.x;
    // band LUT: columns {j, j+4, j+8, j+12} sum to 30 -> every CU's 4
    // resident blocks (stride-256 pattern) total 34 rounds. Heavy first.
    const int band = (int)((0x4501763298DCABEFULL >> ((blk >> 6) << 2)) & 0xF);
    const int rest = blk & 63;
    const int b    = rest >> 3;
    const int s    = rest & 7;            // 4-query slice within band
    const int n    = lane & 15, quad = lane >> 4;
    const int q    = band * 32 + s * 4 + w;
    const int bq   = b * 512 + q;
    const int cmax = band;                // q>>5 == band by construction

    const float* wmf = ws + WS_WMF;
    const float* hq  = ws + WS_HQ;
    const unsigned short* bfp = (const unsigned short*)(ws + WS_BF);
    const unsigned short* xep = (const unsigned short*)(ws + WS_XE);

    const float pa  = prelu_a[0];
    const float b2v = b2[0];

    __shared__ uint4 bufS[2][512];     // score frags: 8 KB per buffer
    __shared__ unsigned strip[4][16];  // per-wave packed score strip

    // W2 (fx4), one-hot, perm sel
    fx4 w2v[4];
    #pragma unroll
    for (int ht = 0; ht < 4; ++ht)
        w2v[ht] = *(const fx4*)(W2 + ht * 16 + quad * 4);
    sx8 oh[4];
    #pragma unroll
    for (int ht = 0; ht < 4; ++ht) {
        sx8 a;
        #pragma unroll
        for (int jj = 0; jj < 8; ++jj) {
            int hp = (ht >> 1) * 32 + quad * 8 + jj;
            a[jj] = (hp == ht * 16 + n) ? (short)0x3F80 : (short)0;
        }
        oh[ht] = a;
    }
    const unsigned sel = (quad < 2) ? 0x05040100u : 0x07060302u;

    // per-query prologue
    fx4 hqv[4];
    #pragma unroll
    for (int ht = 0; ht < 4; ++ht)
        hqv[ht] = *(const fx4*)(hq + bq * 64 + ht * 16 + quad * 4);
    float xq[2][8];
    {
        const float* xp = x + bq * 64 + quad * 8;
        fx4 t0 = *(const fx4*)xp;
        fx4 t1 = *(const fx4*)(xp + 4);
        fx4 t2 = *(const fx4*)(xp + 32);
        fx4 t3 = *(const fx4*)(xp + 36);
        #pragma unroll
        for (int jj = 0; jj < 4; ++jj) {
            xq[0][jj] = t0[jj]; xq[0][4 + jj] = t1[jj];
            xq[1][jj] = t2[jj]; xq[1][4 + jj] = t3[jj];
        }
    }
    sx8 afrag[4][2];
    #pragma unroll
    for (int ht = 0; ht < 4; ++ht)
        #pragma unroll
        for (int hf = 0; hf < 2; ++hf) {
            const float* wp = wmf + (((ht * 2 + hf) * 64 + lane) << 3);
            fx4 w0 = *(const fx4*)wp;
            fx4 w1 = *(const fx4*)(wp + 4);
            sx8 a;
            #pragma unroll
            for (int jj = 0; jj < 4; ++jj) {
                a[jj]     = (short)f2bf(w0[jj] * xq[hf][jj]);
                a[4 + jj] = (short)f2bf(w1[jj] * xq[hf][4 + jj]);
            }
            afrag[ht][hf] = a;
        }

    fx4 eacc[4];
    #pragma unroll
    for (int nt = 0; nt < 4; ++nt) eacc[nt] = (fx4){0.f, 0.f, 0.f, 0.f};

    // stage chunk 0 via async DMA; __syncthreads drains vmcnt
    {
        const uint4* sS = (const uint4*)(bfp + (unsigned)(b * 32) * 2048);
        async_cp16(sS + tid,       &bufS[0][tid]);
        async_cp16(sS + tid + 256, &bufS[0][tid + 256]);
    }
    __syncthreads();

    #pragma unroll 1
    for (int c = 0; c <= cmax; ++c) {
        // async-stage next score chunk into the back buffer (DMA, no VGPRs)
        if (c < cmax) {
            const int p2 = (c + 1) & 1;
            const uint4* sS = (const uint4*)(bfp + (unsigned)(b * 32 + 2 * (c + 1)) * 2048);
            async_cp16(sS + tid,       &bufS[p2][tid]);
            async_cp16(sS + tid + 256, &bufS[p2][tid + 256]);
        }

        const int p = c & 1;
        const unsigned short* ls = (const unsigned short*)&bufS[p][0] + (lane << 3);
        sx8 fa0 = *(const sx8*)(ls);
        sx8 fa1 = *(const sx8*)(ls + 512);
        sx8 fa2 = *(const sx8*)(ls + 1024);
        sx8 fa3 = *(const sx8*)(ls + 1536);
        sx8 fb0 = *(const sx8*)(ls + 2048);
        sx8 fb1 = *(const sx8*)(ls + 2560);
        sx8 fb2 = *(const sx8*)(ls + 3072);
        sx8 fb3 = *(const sx8*)(ls + 3584);

        fx4 accA[4], accB[4];
        #pragma unroll
        for (int ht = 0; ht < 4; ++ht) { accA[ht] = hqv[ht]; accB[ht] = hqv[ht]; }
        #pragma unroll
        for (int ht = 0; ht < 4; ++ht) {
            accA[ht] = __builtin_amdgcn_mfma_f32_16x16x32_bf16(afrag[ht][0], fa0, accA[ht], 0, 0, 0);
            accB[ht] = __builtin_amdgcn_mfma_f32_16x16x32_bf16(afrag[ht][0], fb0, accB[ht], 0, 0, 0);
        }
        #pragma unroll
        for (int ht = 0; ht < 4; ++ht) {
            accA[ht] = __builtin_amdgcn_mfma_f32_16x16x32_bf16(afrag[ht][1], fa1, accA[ht], 0, 0, 0);
            accB[ht] = __builtin_amdgcn_mfma_f32_16x16x32_bf16(afrag[ht][1], fb1, accB[ht], 0, 0, 0);
        }
        #pragma unroll
        for (int ht = 0; ht < 4; ++ht) {
            accA[ht] = __builtin_amdgcn_mfma_f32_16x16x32_bf16(oh[ht], (ht < 2) ? fa2 : fa3, accA[ht], 0, 0, 0);
            accB[ht] = __builtin_amdgcn_mfma_f32_16x16x32_bf16(oh[ht], (ht < 2) ? fb2 : fb3, accB[ht], 0, 0, 0);
        }

        // enc-X frags: direct global b128 loads (L1/L2-resident, identical
        // addresses across the 4 waves). Issued here so the ~200cy L2-hit
        // latency hides under the PReLU/reduce/strip epilogue below.
        const unsigned short* le = xep + ((unsigned)(b * 16 + c) * 2048) + (lane << 3);
        sx8 e0 = *(const sx8*)(le);
        sx8 e1 = *(const sx8*)(le + 512);
        sx8 e2 = *(const sx8*)(le + 1024);
        sx8 e3 = *(const sx8*)(le + 1536);

        // PReLU(z)=max(z, pa*z); W2 dot as fx4; quad-reduce
        fx4 s0v = (fx4){0.f, 0.f, 0.f, 0.f};
        fx4 s1v = (fx4){0.f, 0.f, 0.f, 0.f};
        #pragma unroll
        for (int ht = 0; ht < 4; ++ht) {
            fx4 za = accA[ht], zb = accB[ht];
            fx4 ta = __builtin_elementwise_max(za, za * pa);
            fx4 tb = __builtin_elementwise_max(zb, zb * pa);
            s0v = ta * w2v[ht] + s0v;
            s1v = tb * w2v[ht] + s1v;
        }
        float s0 = (s0v[0] + s0v[1]) + (s0v[2] + s0v[3]);
        float s1 = (s1v[0] + s1v[1]) + (s1v[2] + s1v[3]);
        s0 += __shfl_xor(s0, 16, 64);
        s0 += __shfl_xor(s0, 32, 64);
        s1 += __shfl_xor(s1, 16, 64);
        s1 += __shfl_xor(s1, 32, 64);
        int k0 = c * 32 + n;
        s0 = (k0 <= q)      ? s0 + b2v : 0.f;
        s1 = (k0 + 16 <= q) ? s1 + b2v : 0.f;

        // scores -> A-frag via per-wave LDS strip (in-wave order)
        unsigned packed = (unsigned)f2bf(s0) | ((unsigned)f2bf(s1) << 16);
        if (quad == 0) strip[w][n] = packed;
        const unsigned* sp = &strip[w][(quad & 1) * 8];
        uint4 wv0 = *(const uint4*)sp;
        uint4 wv1 = *(const uint4*)(sp + 4);
        ix4 sw_;
        sw_[0] = (int)__builtin_amdgcn_perm(wv0.y, wv0.x, sel);
        sw_[1] = (int)__builtin_amdgcn_perm(wv0.w, wv0.z, sel);
        sw_[2] = (int)__builtin_amdgcn_perm(wv1.y, wv1.x, sel);
        sw_[3] = (int)__builtin_amdgcn_perm(wv1.w, wv1.z, sel);
        sx8 sfrag = __builtin_bit_cast(sx8, sw_);

        eacc[0] = __builtin_amdgcn_mfma_f32_16x16x32_bf16(sfrag, e0, eacc[0], 0, 0, 0);
        eacc[1] = __builtin_amdgcn_mfma_f32_16x16x32_bf16(sfrag, e1, eacc[1], 0, 0, 0);
        eacc[2] = __builtin_amdgcn_mfma_f32_16x16x32_bf16(sfrag, e2, eacc[2], 0, 0, 0);
        eacc[3] = __builtin_amdgcn_mfma_f32_16x16x32_bf16(sfrag, e3, eacc[3], 0, 0, 0);

        // barrier: drains DMA (vmcnt) + protects buffer swap
        __syncthreads();
    }

    // all m-rows identical; lane's d = quad*16 + n = lane
    float ov = eacc[0][0];
    if (quad == 1) ov = eacc[1][0];
    if (quad == 2) ov = eacc[2][0];
    if (quad == 3) ov = eacc[3][0];
    out[bq * 64 + lane] = ov;
}

extern "C" void kernel_launch(void* const* d_in, const int* in_sizes, int n_in,
                              void* d_out, int out_size, void* d_ws, size_t ws_size,
                              hipStream_t stream) {
    const float* x   = (const float*)d_in[1];
    const float* vmk = (const float*)d_in[2];
    const float* W1  = (const float*)d_in[3];
    const float* b1  = (const float*)d_in[4];
    const float* pa  = (const float*)d_in[5];
    const float* W2  = (const float*)d_in[6];
    const float* b2  = (const float*)d_in[7];
    float* ws  = (float*)d_ws;
    float* out = (float*)d_out;

    hipLaunchKernelGGL(prep, dim3(256), dim3(256), 0, stream,
                       x, vmk, W1, b1, ws);
    hipLaunchKernelGGL(k2_main, dim3(1024), dim3(256), 0, stream,
                       x, pa, W2, b2, ws, out);
}